// Round 4
// baseline (1022.127 us; speedup 1.0000x reference)
//
#include <hip/hip_runtime.h>
#include <stdint.h>

typedef __attribute__((ext_vector_type(8))) short bf16x8;
typedef __attribute__((ext_vector_type(4))) float f32x4;

__device__ __forceinline__ float b2f(short h) {
  return __uint_as_float(((unsigned)(unsigned short)h) << 16);
}
__device__ __forceinline__ short f2b(float f) {
  unsigned u = __float_as_uint(f);
  u += 0x7fffu + ((u >> 16) & 1u);
  return (short)(u >> 16);
}

// ---------------- row sums of P (bf16, 2048 cols) -> store 1/sum ----------------
__global__ __launch_bounds__(256) void rowsum_kernel(const short* __restrict__ P,
                                                     float* __restrict__ invL) {
  int wave = threadIdx.x >> 6, lane = threadIdx.x & 63;
  size_t row = (size_t)blockIdx.x * 4 + wave;
  const short* p = P + row * 2048;
  float s = 0.f;
#pragma unroll
  for (int it = 0; it < 4; ++it) {
    bf16x8 x = *reinterpret_cast<const bf16x8*>(&p[it * 512 + lane * 8]);
#pragma unroll
    for (int j = 0; j < 8; ++j) s += b2f(x[j]);
  }
#pragma unroll
  for (int m = 32; m; m >>= 1) s += __shfl_xor(s, m);
  if (lane == 0) invL[row] = 1.0f / s;
}

// =================================================================================
// gemm_split: C[m,n] = sum over NSEG segments of Aseg[m,k]*Bseg[n,k]:
//   seg0: Ahi*Bhi, seg1: Ahi*Blo, seg2: Alo*Bhi
// AF32/BF32: operand given fp32; hi/lo derived during staging.
// MODE 5: bias add, split-store bf16 hi->C, lo->C2
// MODE 6: bias add, store bf16 hi only -> C
// MODE 1: store bf16 exp(acc - 20)
// =================================================================================
template <int MODE, int NSEG, bool AF32, bool BF32>
__global__ __launch_bounds__(256) void gemm_split(
    const void* __restrict__ A0, const short* __restrict__ Alo,
    const void* __restrict__ B0, const short* __restrict__ Blo,
    void* __restrict__ C, short* __restrict__ C2, const float* __restrict__ bias,
    int K0, int ldA, int ldB, int ldC, long sA, long sB, long sC) {
  __shared__ alignas(16) short As[128 * 32];
  __shared__ alignas(16) short Bs[128 * 32];
  const int tid = threadIdx.x;
  const int z = blockIdx.z;
  const int rowBase = blockIdx.y * 128;
  const int colBase = blockIdx.x * 128;
  const int lane = tid & 63;
  const int ln = lane & 15;
  const int qd = lane >> 4;
  const int w = tid >> 6;
  const int wr = w >> 1, wc = w & 1;

  f32x4 acc[4][4];
#pragma unroll
  for (int i = 0; i < 4; ++i)
#pragma unroll
    for (int j = 0; j < 4; ++j) acc[i][j] = 0.f;

  for (int seg = 0; seg < NSEG; ++seg) {
    const bool loA = (seg == 2);
    const bool loB = (seg == 1);
    for (int ko = 0; ko < K0; ko += 32) {
      if constexpr (AF32) {
        const float* Af = (const float*)A0 + (size_t)z * sA;
#pragma unroll
        for (int q = 0; q < 2; ++q) {
          int c = q * 256 + tid;
          int r = c >> 2;
          int k0 = (c & 3) << 3;
          const float* p = &Af[(size_t)(rowBase + r) * ldA + ko + k0];
          float4 v0 = *reinterpret_cast<const float4*>(p);
          float4 v1 = *reinterpret_cast<const float4*>(p + 4);
          float vv[8] = {v0.x, v0.y, v0.z, v0.w, v1.x, v1.y, v1.z, v1.w};
          bf16x8 t;
#pragma unroll
          for (int s = 0; s < 8; ++s) {
            short h = f2b(vv[s]);
            t[s] = loA ? f2b(vv[s] - b2f(h)) : h;
          }
          *reinterpret_cast<bf16x8*>(&As[r * 32 + (k0 ^ ((r & 3) << 3))]) = t;
        }
      } else {
        const short* Ap = (loA ? Alo : (const short*)A0) + (size_t)z * sA;
#pragma unroll
        for (int q = 0; q < 2; ++q) {
          int c = q * 256 + tid;
          int r = c >> 2;
          int k0 = (c & 3) << 3;
          uint4 v = *reinterpret_cast<const uint4*>(&Ap[(size_t)(rowBase + r) * ldA + ko + k0]);
          *reinterpret_cast<uint4*>(&As[r * 32 + (k0 ^ ((r & 3) << 3))]) = v;
        }
      }
      if constexpr (BF32) {
        const float* Bf = (const float*)B0 + (size_t)z * sB;
#pragma unroll
        for (int q = 0; q < 2; ++q) {
          int c = q * 256 + tid;
          int r = c >> 2;
          int k0 = (c & 3) << 3;
          const float* p = &Bf[(size_t)(colBase + r) * ldB + ko + k0];
          float4 v0 = *reinterpret_cast<const float4*>(p);
          float4 v1 = *reinterpret_cast<const float4*>(p + 4);
          float vv[8] = {v0.x, v0.y, v0.z, v0.w, v1.x, v1.y, v1.z, v1.w};
          bf16x8 t;
#pragma unroll
          for (int s = 0; s < 8; ++s) {
            short h = f2b(vv[s]);
            t[s] = loB ? f2b(vv[s] - b2f(h)) : h;
          }
          *reinterpret_cast<bf16x8*>(&Bs[r * 32 + (k0 ^ ((r & 3) << 3))]) = t;
        }
      } else {
        const short* Bp = (loB ? Blo : (const short*)B0) + (size_t)z * sB;
#pragma unroll
        for (int q = 0; q < 2; ++q) {
          int c = q * 256 + tid;
          int r = c >> 2;
          int k0 = (c & 3) << 3;
          uint4 v = *reinterpret_cast<const uint4*>(&Bp[(size_t)(colBase + r) * ldB + ko + k0]);
          *reinterpret_cast<uint4*>(&Bs[r * 32 + (k0 ^ ((r & 3) << 3))]) = v;
        }
      }
      __syncthreads();
      bf16x8 af[4], bfv[4];
#pragma unroll
      for (int rt = 0; rt < 4; ++rt) {
        int m = wr * 64 + rt * 16 + ln;
        af[rt] = *reinterpret_cast<const bf16x8*>(&As[m * 32 + ((qd * 8) ^ ((m & 3) << 3))]);
      }
#pragma unroll
      for (int ct = 0; ct < 4; ++ct) {
        int n = wc * 64 + ct * 16 + ln;
        bfv[ct] = *reinterpret_cast<const bf16x8*>(&Bs[n * 32 + ((qd * 8) ^ ((n & 3) << 3))]);
      }
#pragma unroll
      for (int rt = 0; rt < 4; ++rt)
#pragma unroll
        for (int ct = 0; ct < 4; ++ct)
          acc[rt][ct] =
              __builtin_amdgcn_mfma_f32_16x16x32_bf16(af[rt], bfv[ct], acc[rt][ct], 0, 0, 0);
      __syncthreads();
    }
  }

  // epilogue: C/D layout col = lane&15, row = (lane>>4)*4 + reg
#pragma unroll
  for (int rt = 0; rt < 4; ++rt) {
    int row0 = rowBase + wr * 64 + rt * 16 + qd * 4;
#pragma unroll
    for (int ct = 0; ct < 4; ++ct) {
      int col = colBase + wc * 64 + ct * 16 + ln;
      f32x4 a = acc[rt][ct];
      if constexpr (MODE == 5) {
        short* Chi = (short*)C + (size_t)z * sC;
        short* Clo = C2 + (size_t)z * sC;
        float bb = bias[col];
#pragma unroll
        for (int r = 0; r < 4; ++r) {
          float val = a[r] + bb;
          short h = f2b(val);
          Chi[(size_t)(row0 + r) * ldC + col] = h;
          Clo[(size_t)(row0 + r) * ldC + col] = f2b(val - b2f(h));
        }
      } else if constexpr (MODE == 6) {
        short* Co = (short*)C + (size_t)z * sC;
        float bb = bias[col];
#pragma unroll
        for (int r = 0; r < 4; ++r) Co[(size_t)(row0 + r) * ldC + col] = f2b(a[r] + bb);
      } else {  // MODE 1
        short* Co = (short*)C + (size_t)z * sC;
#pragma unroll
        for (int r = 0; r < 4; ++r)
          Co[(size_t)(row0 + r) * ldC + col] = f2b(__expf(a[r] - 20.0f));
      }
    }
  }
}

// =================================================================================
// gemm_k: C[m,n] = sum_k A[m,k]*B[n,k], plain bf16.
// TA/TB: operand supplied as [K, M]/[K, N] -> register-transpose staging.
// SB: scale B element at depth k by invL[k]. BF32: B supplied fp32.
// DUALA: A columns [0,768) from A, [768,1536) from A2 (both ld = 768).
// MODE 2: bf16 = acc * invL[row]; MODE 3: bf16 = acc; MODE 4: fp32 = acc + bias[col]
// =================================================================================
template <int MODE, bool TA, bool TB, bool SB, bool BF32, bool DUALA>
__global__ __launch_bounds__(256) void gemm_k(const short* __restrict__ A,
                                              const short* __restrict__ A2,
                                              const void* __restrict__ B,
                                              void* __restrict__ C,
                                              const float* __restrict__ bias,
                                              const float* __restrict__ invL,
                                              int K, int ldA, int ldB, int ldC,
                                              long sA, long sB, long sC, long sL) {
  __shared__ alignas(16) short As[128 * 32];
  __shared__ alignas(16) short Bs[128 * 32];
  const int tid = threadIdx.x;
  const int z = blockIdx.z;
  const short* Az = A + (size_t)z * sA;
  const float* Lz = invL ? (invL + (size_t)z * sL) : nullptr;
  const int rowBase = blockIdx.y * 128;
  const int colBase = blockIdx.x * 128;
  const int lane = tid & 63;
  const int ln = lane & 15;
  const int qd = lane >> 4;
  const int w = tid >> 6;
  const int wr = w >> 1, wc = w & 1;

  f32x4 acc[4][4];
#pragma unroll
  for (int i = 0; i < 4; ++i)
#pragma unroll
    for (int j = 0; j < 4; ++j) acc[i][j] = 0.f;

  for (int kb = 0; kb < K; kb += 32) {
    // ---- stage A ----
    if constexpr (!TA) {
#pragma unroll
      for (int q = 0; q < 2; ++q) {
        int c = q * 256 + tid;
        int r = c >> 2;
        int k0 = (c & 3) << 3;
        int kk = kb + k0;
        const short* src;
        if constexpr (DUALA) {
          src = (kk < 768) ? &Az[(size_t)(rowBase + r) * 768 + kk]
                           : &A2[(size_t)(rowBase + r) * 768 + kk - 768];
        } else {
          src = &Az[(size_t)(rowBase + r) * ldA + kk];
        }
        uint4 v = *reinterpret_cast<const uint4*>(src);
        *reinterpret_cast<uint4*>(&As[r * 32 + (k0 ^ ((r & 3) << 3))]) = v;
      }
    } else {
#pragma unroll
      for (int q = 0; q < 2; ++q) {
        int task = q * 256 + tid;
        int m = task & 127;
        int kc = (task >> 7) << 3;
        bf16x8 t;
#pragma unroll
        for (int s = 0; s < 8; ++s)
          t[s] = Az[(size_t)(kb + kc + s) * ldA + rowBase + m];
        *reinterpret_cast<bf16x8*>(&As[m * 32 + (kc ^ ((m & 3) << 3))]) = t;
      }
    }
    // ---- stage B ----
    if constexpr (TB) {
      const short* Bz = (const short*)B + (size_t)z * sB;
#pragma unroll
      for (int q = 0; q < 2; ++q) {
        int task = q * 256 + tid;
        int n = task & 127;
        int kc = (task >> 7) << 3;
        bf16x8 t;
#pragma unroll
        for (int s = 0; s < 8; ++s) {
          short v = Bz[(size_t)(kb + kc + s) * ldB + colBase + n];
          if constexpr (SB) v = f2b(b2f(v) * Lz[kb + kc + s]);
          t[s] = v;
        }
        *reinterpret_cast<bf16x8*>(&Bs[n * 32 + (kc ^ ((n & 3) << 3))]) = t;
      }
    } else if constexpr (BF32) {
      const float* Bf = (const float*)B + (size_t)z * sB;
#pragma unroll
      for (int q = 0; q < 2; ++q) {
        int c = q * 256 + tid;
        int r = c >> 2;
        int k0 = (c & 3) << 3;
        const float* p = &Bf[(size_t)(colBase + r) * ldB + kb + k0];
        float4 v0 = *reinterpret_cast<const float4*>(p);
        float4 v1 = *reinterpret_cast<const float4*>(p + 4);
        float vv[8] = {v0.x, v0.y, v0.z, v0.w, v1.x, v1.y, v1.z, v1.w};
        bf16x8 t;
#pragma unroll
        for (int s = 0; s < 8; ++s) t[s] = f2b(vv[s]);
        *reinterpret_cast<bf16x8*>(&Bs[r * 32 + (k0 ^ ((r & 3) << 3))]) = t;
      }
    } else {
      const short* Bz = (const short*)B + (size_t)z * sB;
#pragma unroll
      for (int q = 0; q < 2; ++q) {
        int c = q * 256 + tid;
        int r = c >> 2;
        int k0 = (c & 3) << 3;
        uint4 v = *reinterpret_cast<const uint4*>(&Bz[(size_t)(colBase + r) * ldB + kb + k0]);
        *reinterpret_cast<uint4*>(&Bs[r * 32 + (k0 ^ ((r & 3) << 3))]) = v;
      }
    }
    __syncthreads();
    bf16x8 af[4], bfv[4];
#pragma unroll
    for (int rt = 0; rt < 4; ++rt) {
      int m = wr * 64 + rt * 16 + ln;
      af[rt] = *reinterpret_cast<const bf16x8*>(&As[m * 32 + ((qd * 8) ^ ((m & 3) << 3))]);
    }
#pragma unroll
    for (int ct = 0; ct < 4; ++ct) {
      int n = wc * 64 + ct * 16 + ln;
      bfv[ct] = *reinterpret_cast<const bf16x8*>(&Bs[n * 32 + ((qd * 8) ^ ((n & 3) << 3))]);
    }
#pragma unroll
    for (int rt = 0; rt < 4; ++rt)
#pragma unroll
      for (int ct = 0; ct < 4; ++ct)
        acc[rt][ct] =
            __builtin_amdgcn_mfma_f32_16x16x32_bf16(af[rt], bfv[ct], acc[rt][ct], 0, 0, 0);
    __syncthreads();
  }

#pragma unroll
  for (int rt = 0; rt < 4; ++rt) {
    int row0 = rowBase + wr * 64 + rt * 16 + qd * 4;
#pragma unroll
    for (int ct = 0; ct < 4; ++ct) {
      int col = colBase + wc * 64 + ct * 16 + ln;
      f32x4 a = acc[rt][ct];
      if constexpr (MODE == 2) {
        short* Co = (short*)C + (size_t)z * sC;
#pragma unroll
        for (int r = 0; r < 4; ++r)
          Co[(size_t)(row0 + r) * ldC + col] = f2b(a[r] * Lz[row0 + r]);
      } else if constexpr (MODE == 3) {
        short* Co = (short*)C + (size_t)z * sC;
#pragma unroll
        for (int r = 0; r < 4; ++r) Co[(size_t)(row0 + r) * ldC + col] = f2b(a[r]);
      } else {  // MODE 4
        float* Co = (float*)C + (size_t)z * sC;
        float bb = bias[col];
#pragma unroll
        for (int r = 0; r < 4; ++r) Co[(size_t)(row0 + r) * ldC + col] = a[r] + bb;
      }
    }
  }
}

extern "C" void kernel_launch(void* const* d_in, const int* in_sizes, int n_in,
                              void* d_out, int out_size, void* d_ws, size_t ws_size,
                              hipStream_t stream) {
  const float* vf = (const float*)d_in[0];
  const float* lf = (const float*)d_in[1];
  const float* Wv = (const float*)d_in[2];
  const float* bv = (const float*)d_in[3];
  const float* Wl = (const float*)d_in[4];
  const float* bl = (const float*)d_in[5];
  const float* Wo = (const float*)d_in[6];
  const float* bo = (const float*)d_in[7];

  constexpr int Bz = 8, L = 2048, D = 768, M = Bz * L, D2 = 2 * D;
  constexpr size_t PLANE = (size_t)M * D;  // elements per bf16 plane

  // ---- workspace layout (92.4 MB total) ----
  char* wp = (char*)d_ws;
  auto alloc = [&](size_t bytes) {
    char* p = wp;
    wp += (bytes + 255) & ~(size_t)255;
    return p;
  };
  short* vp_hi = (short*)alloc(PLANE * 2);               // 25.2 MB; reused as `al` after 2a
  short* P     = (short*)alloc((size_t)Bz * L * L * 2);  // 67.1 MB; reused as out_tmp after 2b
  float* invL  = (float*)alloc((size_t)M * 4);           // 64 KB
  short* al      = vp_hi;       // alias (vp_hi dead after 2a)
  float* out_tmp = (float*)P;   // alias (P dead after 2b); 50.3 <= 67.1 MB

  // ---- d_out doubles as scratch: lp_hi | lp_lo planes (exactly out-bytes) ----
  short* lp_hi = (short*)d_out;
  short* lp_lo = lp_hi + PLANE;
  short* av    = lp_lo;         // alias (lp_lo dead after sim)

  // 1) vp = V*Wv^T + bv -> hi plane only (full 3-seg split from fp32)
  gemm_split<6, 3, true, true><<<dim3(D / 128, M / 128, 1), 256, 0, stream>>>(
      vf, nullptr, Wv, nullptr, vp_hi, nullptr, bv, D, D, D, D, 0, 0, 0);
  // 2) lp = L*Wl^T + bl -> hi+lo planes (into d_out)
  gemm_split<5, 3, true, true><<<dim3(D / 128, M / 128, 1), 256, 0, stream>>>(
      lf, nullptr, Wl, nullptr, lp_hi, lp_lo, bl, D, D, D, D, 0, 0, 0);

  // 3) P = exp(vp*lp^T - 20): 2 segments (vp_hi*lp_hi + vp_hi*lp_lo)
  gemm_split<1, 2, false, false><<<dim3(L / 128, L / 128, Bz), 256, 0, stream>>>(
      vp_hi, nullptr, lp_hi, lp_lo, P, nullptr, nullptr, D, D, D, L,
      (long)L * D, (long)L * D, (long)L * L);

  // 4) invL[row] = 1 / sum_j P[row, j]
  rowsum_kernel<<<dim3(M / 4), 256, 0, stream>>>(P, invL);

  // 5) aligned_vision = (P @ vp) * invL[row] -> av  (over dead lp_lo in d_out)
  gemm_k<2, false, true, false, false, false><<<dim3(D / 128, L / 128, Bz), 256, 0, stream>>>(
      P, nullptr, vp_hi, av, nullptr, invL, L, L, D, D, (long)L * L, (long)L * D,
      (long)L * D, (long)L);

  // 6) aligned_language = P^T @ (lp * invL[k]) -> al  (over dead vp_hi in ws)
  gemm_k<3, true, true, true, false, false><<<dim3(D / 128, L / 128, Bz), 256, 0, stream>>>(
      P, nullptr, lp_hi, al, nullptr, invL, L, L, D, D, (long)L * L, (long)L * D,
      (long)L * D, (long)L);

  // 7) out = [av | al] @ Wo^T + bo -> out_tmp (over dead P), fp32
  gemm_k<4, false, false, false, true, true><<<dim3(D / 128, M / 128, 1), 256, 0, stream>>>(
      av, al, Wo, out_tmp, bo, nullptr, D2, D, D2, D, 0, 0, 0, 0);

  // 8) out_tmp -> d_out (lp planes dead; capture-legal async d2d copy)
  hipMemcpyAsync(d_out, out_tmp, (size_t)M * D * 4, hipMemcpyDeviceToDevice, stream);
}

// Round 5
// 710.874 us; speedup vs baseline: 1.4378x; 1.4378x over previous
//
#include <hip/hip_runtime.h>
#include <stdint.h>

typedef __attribute__((ext_vector_type(8))) short bf16x8;
typedef __attribute__((ext_vector_type(4))) float f32x4;

__device__ __forceinline__ float b2f(short h) {
  return __uint_as_float(((unsigned)(unsigned short)h) << 16);
}
__device__ __forceinline__ short f2b(float f) {
  unsigned u = __float_as_uint(f);
  u += 0x7fffu + ((u >> 16) & 1u);
  return (short)(u >> 16);
}

// async global->LDS, 16 B per lane (global_load_lds_dwordx4)
__device__ __forceinline__ void glds16(const void* g, void* l) {
  __builtin_amdgcn_global_load_lds(
      (const __attribute__((address_space(1))) void*)g,
      (__attribute__((address_space(3))) void*)l, 16, 0, 0);
}

// ---------------- row sums of P (bf16, 2048 cols) -> store 1/sum ----------------
__global__ __launch_bounds__(256) void rowsum_kernel(const short* __restrict__ P,
                                                     float* __restrict__ invL) {
  int wave = threadIdx.x >> 6, lane = threadIdx.x & 63;
  size_t row = (size_t)blockIdx.x * 4 + wave;
  const short* p = P + row * 2048;
  float s = 0.f;
#pragma unroll
  for (int it = 0; it < 4; ++it) {
    bf16x8 x = *reinterpret_cast<const bf16x8*>(&p[it * 512 + lane * 8]);
#pragma unroll
    for (int j = 0; j < 8; ++j) s += b2f(x[j]);
  }
#pragma unroll
  for (int m = 32; m; m >>= 1) s += __shfl_xor(s, m);
  if (lane == 0) invL[row] = 1.0f / s;
}

// =================================================================================
// proj3: fused 3-segment split projection, both projections in one dispatch (z).
// C = (Ahi+Alo)*(Bhi+Blo)^T + bias ~= Ahi*Bhi + Alo*Bhi + Ahi*Blo, computed
// per-K-tile with fp32 operands fetched ONCE and split in registers.
// z==0: A=Vf,B=Wv,bias=bv -> vp_hi.   z==1: A=Lf,B=Wl,bias=bl -> lp_hi + lp_lo.
// =================================================================================
__global__ __launch_bounds__(256) void proj3_kernel(
    const float* __restrict__ Vf, const float* __restrict__ Lf,
    const float* __restrict__ Wv, const float* __restrict__ Wl,
    const float* __restrict__ bv, const float* __restrict__ bl,
    short* __restrict__ vp_hi, short* __restrict__ lp_hi, short* __restrict__ lp_lo) {
  __shared__ alignas(16) short AsH[128 * 32];
  __shared__ alignas(16) short AsL[128 * 32];
  __shared__ alignas(16) short BsH[128 * 32];
  __shared__ alignas(16) short BsL[128 * 32];
  const int tid = threadIdx.x;
  const int z = blockIdx.z;
  const float* Af = z ? Lf : Vf;
  const float* Bf = z ? Wl : Wv;
  const float* bias = z ? bl : bv;
  const int rowBase = blockIdx.y * 128;
  const int colBase = blockIdx.x * 128;
  const int lane = tid & 63;
  const int ln = lane & 15;
  const int qd = lane >> 4;
  const int w = tid >> 6;
  const int wr = w >> 1, wc = w & 1;

  f32x4 acc[4][4];
#pragma unroll
  for (int i = 0; i < 4; ++i)
#pragma unroll
    for (int j = 0; j < 4; ++j) acc[i][j] = 0.f;

  for (int kb = 0; kb < 768; kb += 32) {
    // stage A and B fp32 tiles once; split into hi/lo bf16 planes in regs
#pragma unroll
    for (int q = 0; q < 2; ++q) {
      int c = q * 256 + tid;
      int r = c >> 2;
      int k0 = (c & 3) << 3;
      int sw = k0 ^ ((r & 3) << 3);
      {
        const float* p = &Af[(size_t)(rowBase + r) * 768 + kb + k0];
        float4 v0 = *reinterpret_cast<const float4*>(p);
        float4 v1 = *reinterpret_cast<const float4*>(p + 4);
        float vv[8] = {v0.x, v0.y, v0.z, v0.w, v1.x, v1.y, v1.z, v1.w};
        bf16x8 th, tl;
#pragma unroll
        for (int s = 0; s < 8; ++s) {
          short h = f2b(vv[s]);
          th[s] = h;
          tl[s] = f2b(vv[s] - b2f(h));
        }
        *reinterpret_cast<bf16x8*>(&AsH[r * 32 + sw]) = th;
        *reinterpret_cast<bf16x8*>(&AsL[r * 32 + sw]) = tl;
      }
      {
        const float* p = &Bf[(size_t)(colBase + r) * 768 + kb + k0];
        float4 v0 = *reinterpret_cast<const float4*>(p);
        float4 v1 = *reinterpret_cast<const float4*>(p + 4);
        float vv[8] = {v0.x, v0.y, v0.z, v0.w, v1.x, v1.y, v1.z, v1.w};
        bf16x8 th, tl;
#pragma unroll
        for (int s = 0; s < 8; ++s) {
          short h = f2b(vv[s]);
          th[s] = h;
          tl[s] = f2b(vv[s] - b2f(h));
        }
        *reinterpret_cast<bf16x8*>(&BsH[r * 32 + sw]) = th;
        *reinterpret_cast<bf16x8*>(&BsL[r * 32 + sw]) = tl;
      }
    }
    __syncthreads();
    bf16x8 ah[4], bh[4], tf[4];
#pragma unroll
    for (int rt = 0; rt < 4; ++rt) {
      int m = wr * 64 + rt * 16 + ln;
      ah[rt] = *reinterpret_cast<const bf16x8*>(&AsH[m * 32 + ((qd * 8) ^ ((m & 3) << 3))]);
    }
#pragma unroll
    for (int ct = 0; ct < 4; ++ct) {
      int n = wc * 64 + ct * 16 + ln;
      bh[ct] = *reinterpret_cast<const bf16x8*>(&BsH[n * 32 + ((qd * 8) ^ ((n & 3) << 3))]);
    }
#pragma unroll
    for (int rt = 0; rt < 4; ++rt)
#pragma unroll
      for (int ct = 0; ct < 4; ++ct)
        acc[rt][ct] = __builtin_amdgcn_mfma_f32_16x16x32_bf16(ah[rt], bh[ct], acc[rt][ct], 0, 0, 0);
    // A_lo * B_hi
#pragma unroll
    for (int rt = 0; rt < 4; ++rt) {
      int m = wr * 64 + rt * 16 + ln;
      tf[rt] = *reinterpret_cast<const bf16x8*>(&AsL[m * 32 + ((qd * 8) ^ ((m & 3) << 3))]);
    }
#pragma unroll
    for (int rt = 0; rt < 4; ++rt)
#pragma unroll
      for (int ct = 0; ct < 4; ++ct)
        acc[rt][ct] = __builtin_amdgcn_mfma_f32_16x16x32_bf16(tf[rt], bh[ct], acc[rt][ct], 0, 0, 0);
    // A_hi * B_lo
#pragma unroll
    for (int ct = 0; ct < 4; ++ct) {
      int n = wc * 64 + ct * 16 + ln;
      tf[ct] = *reinterpret_cast<const bf16x8*>(&BsL[n * 32 + ((qd * 8) ^ ((n & 3) << 3))]);
    }
#pragma unroll
    for (int rt = 0; rt < 4; ++rt)
#pragma unroll
      for (int ct = 0; ct < 4; ++ct)
        acc[rt][ct] = __builtin_amdgcn_mfma_f32_16x16x32_bf16(ah[rt], tf[ct], acc[rt][ct], 0, 0, 0);
    __syncthreads();
  }

#pragma unroll
  for (int rt = 0; rt < 4; ++rt) {
    int row0 = rowBase + wr * 64 + rt * 16 + qd * 4;
#pragma unroll
    for (int ct = 0; ct < 4; ++ct) {
      int col = colBase + wc * 64 + ct * 16 + ln;
      float bb = bias[col];
      f32x4 a = acc[rt][ct];
      if (z == 0) {
#pragma unroll
        for (int r = 0; r < 4; ++r)
          vp_hi[(size_t)(row0 + r) * 768 + col] = f2b(a[r] + bb);
      } else {
#pragma unroll
        for (int r = 0; r < 4; ++r) {
          float val = a[r] + bb;
          short h = f2b(val);
          lp_hi[(size_t)(row0 + r) * 768 + col] = h;
          lp_lo[(size_t)(row0 + r) * 768 + col] = f2b(val - b2f(h));
        }
      }
    }
  }
}

// =================================================================================
// sim2: P = exp(vp_hi*(lp_hi+lp_lo)^T - 20), fused 2 products per K-tile.
// All three operands are plain row-major bf16 -> global_load_lds staging.
// Plain (unswizzled) LDS layout [r][32] — matches glds lane order.
// =================================================================================
__global__ __launch_bounds__(256) void sim2_kernel(const short* __restrict__ vp,
                                                   const short* __restrict__ lph,
                                                   const short* __restrict__ lpl,
                                                   short* __restrict__ P) {
  __shared__ alignas(16) short As[128 * 32];
  __shared__ alignas(16) short Bh[128 * 32];
  __shared__ alignas(16) short Bl[128 * 32];
  const int tid = threadIdx.x;
  const int z = blockIdx.z;
  const short* Az = vp + (size_t)z * 2048 * 768;
  const short* B0 = lph + (size_t)z * 2048 * 768;
  const short* B1 = lpl + (size_t)z * 2048 * 768;
  const int rowBase = blockIdx.y * 128;
  const int colBase = blockIdx.x * 128;
  const int lane = tid & 63;
  const int ln = lane & 15;
  const int qd = lane >> 4;
  const int w = tid >> 6;
  const int wr = w >> 1, wc = w & 1;

  f32x4 acc[4][4];
#pragma unroll
  for (int i = 0; i < 4; ++i)
#pragma unroll
    for (int j = 0; j < 4; ++j) acc[i][j] = 0.f;

  for (int kb = 0; kb < 768; kb += 32) {
#pragma unroll
    for (int q = 0; q < 2; ++q) {
      int c = q * 256 + tid;
      int r = c >> 2;
      int k0 = (c & 3) << 3;
      glds16(&Az[(size_t)(rowBase + r) * 768 + kb + k0], &As[c * 8]);
      glds16(&B0[(size_t)(colBase + r) * 768 + kb + k0], &Bh[c * 8]);
      glds16(&B1[(size_t)(colBase + r) * 768 + kb + k0], &Bl[c * 8]);
    }
    __syncthreads();
    bf16x8 af[4], bf[4];
#pragma unroll
    for (int rt = 0; rt < 4; ++rt)
      af[rt] = *reinterpret_cast<const bf16x8*>(&As[(wr * 64 + rt * 16 + ln) * 32 + qd * 8]);
#pragma unroll
    for (int ct = 0; ct < 4; ++ct)
      bf[ct] = *reinterpret_cast<const bf16x8*>(&Bh[(wc * 64 + ct * 16 + ln) * 32 + qd * 8]);
#pragma unroll
    for (int rt = 0; rt < 4; ++rt)
#pragma unroll
      for (int ct = 0; ct < 4; ++ct)
        acc[rt][ct] = __builtin_amdgcn_mfma_f32_16x16x32_bf16(af[rt], bf[ct], acc[rt][ct], 0, 0, 0);
#pragma unroll
    for (int ct = 0; ct < 4; ++ct)
      bf[ct] = *reinterpret_cast<const bf16x8*>(&Bl[(wc * 64 + ct * 16 + ln) * 32 + qd * 8]);
#pragma unroll
    for (int rt = 0; rt < 4; ++rt)
#pragma unroll
      for (int ct = 0; ct < 4; ++ct)
        acc[rt][ct] = __builtin_amdgcn_mfma_f32_16x16x32_bf16(af[rt], bf[ct], acc[rt][ct], 0, 0, 0);
    __syncthreads();
  }

  short* Pz = P + (size_t)z * 2048 * 2048;
#pragma unroll
  for (int rt = 0; rt < 4; ++rt) {
    int row0 = rowBase + wr * 64 + rt * 16 + qd * 4;
#pragma unroll
    for (int ct = 0; ct < 4; ++ct) {
      int col = colBase + wc * 64 + ct * 16 + ln;
      f32x4 a = acc[rt][ct];
#pragma unroll
      for (int r = 0; r < 4; ++r)
        Pz[(size_t)(row0 + r) * 2048 + col] = f2b(__expf(a[r] - 20.0f));
    }
  }
}

// =================================================================================
// gemm_k: C[m,n] = sum_k A[m,k]*B[n,k], plain bf16.
// Plain operands use global_load_lds (unswizzled layout); TA/TB/BF32 use VGPR
// staging with XOR-swizzled layout. SB scales B by invL[k]. DUALA: A split 768|768.
// MODE 2: bf16 = acc * invL[row]; MODE 3: bf16 = acc; MODE 4: fp32 = acc + bias[col]
// =================================================================================
template <int MODE, bool TA, bool TB, bool SB, bool BF32, bool DUALA>
__global__ __launch_bounds__(256) void gemm_k(const short* __restrict__ A,
                                              const short* __restrict__ A2,
                                              const void* __restrict__ B,
                                              void* __restrict__ C,
                                              const float* __restrict__ bias,
                                              const float* __restrict__ invL,
                                              int K, int ldA, int ldB, int ldC,
                                              long sA, long sB, long sC, long sL) {
  __shared__ alignas(16) short As[128 * 32];
  __shared__ alignas(16) short Bs[128 * 32];
  const int tid = threadIdx.x;
  const int z = blockIdx.z;
  const short* Az = A + (size_t)z * sA;
  const float* Lz = invL ? (invL + (size_t)z * sL) : nullptr;
  const int rowBase = blockIdx.y * 128;
  const int colBase = blockIdx.x * 128;
  const int lane = tid & 63;
  const int ln = lane & 15;
  const int qd = lane >> 4;
  const int w = tid >> 6;
  const int wr = w >> 1, wc = w & 1;
  constexpr bool GA = !TA;               // A via glds, plain layout
  constexpr bool GB = !TB && !BF32;      // B via glds, plain layout

  f32x4 acc[4][4];
#pragma unroll
  for (int i = 0; i < 4; ++i)
#pragma unroll
    for (int j = 0; j < 4; ++j) acc[i][j] = 0.f;

  for (int kb = 0; kb < K; kb += 32) {
    // ---- stage A ----
    if constexpr (GA) {
#pragma unroll
      for (int q = 0; q < 2; ++q) {
        int c = q * 256 + tid;
        int r = c >> 2;
        int k0 = (c & 3) << 3;
        int kk = kb + k0;
        const short* src;
        if constexpr (DUALA) {
          src = (kk < 768) ? &Az[(size_t)(rowBase + r) * 768 + kk]
                           : &A2[(size_t)(rowBase + r) * 768 + kk - 768];
        } else {
          src = &Az[(size_t)(rowBase + r) * ldA + kk];
        }
        glds16(src, &As[c * 8]);
      }
    } else {
#pragma unroll
      for (int q = 0; q < 2; ++q) {
        int task = q * 256 + tid;
        int m = task & 127;
        int kc = (task >> 7) << 3;
        bf16x8 t;
#pragma unroll
        for (int s = 0; s < 8; ++s)
          t[s] = Az[(size_t)(kb + kc + s) * ldA + rowBase + m];
        *reinterpret_cast<bf16x8*>(&As[m * 32 + (kc ^ ((m & 3) << 3))]) = t;
      }
    }
    // ---- stage B ----
    if constexpr (TB) {
      const short* Bz = (const short*)B + (size_t)z * sB;
#pragma unroll
      for (int q = 0; q < 2; ++q) {
        int task = q * 256 + tid;
        int n = task & 127;
        int kc = (task >> 7) << 3;
        bf16x8 t;
#pragma unroll
        for (int s = 0; s < 8; ++s) {
          short v = Bz[(size_t)(kb + kc + s) * ldB + colBase + n];
          if constexpr (SB) v = f2b(b2f(v) * Lz[kb + kc + s]);
          t[s] = v;
        }
        *reinterpret_cast<bf16x8*>(&Bs[n * 32 + (kc ^ ((n & 3) << 3))]) = t;
      }
    } else if constexpr (BF32) {
      const float* Bf = (const float*)B + (size_t)z * sB;
#pragma unroll
      for (int q = 0; q < 2; ++q) {
        int c = q * 256 + tid;
        int r = c >> 2;
        int k0 = (c & 3) << 3;
        const float* p = &Bf[(size_t)(colBase + r) * ldB + kb + k0];
        float4 v0 = *reinterpret_cast<const float4*>(p);
        float4 v1 = *reinterpret_cast<const float4*>(p + 4);
        float vv[8] = {v0.x, v0.y, v0.z, v0.w, v1.x, v1.y, v1.z, v1.w};
        bf16x8 t;
#pragma unroll
        for (int s = 0; s < 8; ++s) t[s] = f2b(vv[s]);
        *reinterpret_cast<bf16x8*>(&Bs[r * 32 + (k0 ^ ((r & 3) << 3))]) = t;
      }
    } else {
      const short* Bz = (const short*)B + (size_t)z * sB;
#pragma unroll
      for (int q = 0; q < 2; ++q) {
        int c = q * 256 + tid;
        int r = c >> 2;
        int k0 = (c & 3) << 3;
        glds16(&Bz[(size_t)(colBase + r) * ldB + kb + k0], &Bs[c * 8]);
      }
    }
    __syncthreads();
    bf16x8 af[4], bfv[4];
#pragma unroll
    for (int rt = 0; rt < 4; ++rt) {
      int m = wr * 64 + rt * 16 + ln;
      int off = GA ? (qd * 8) : ((qd * 8) ^ ((m & 3) << 3));
      af[rt] = *reinterpret_cast<const bf16x8*>(&As[m * 32 + off]);
    }
#pragma unroll
    for (int ct = 0; ct < 4; ++ct) {
      int n = wc * 64 + ct * 16 + ln;
      int off = GB ? (qd * 8) : ((qd * 8) ^ ((n & 3) << 3));
      bfv[ct] = *reinterpret_cast<const bf16x8*>(&Bs[n * 32 + off]);
    }
#pragma unroll
    for (int rt = 0; rt < 4; ++rt)
#pragma unroll
      for (int ct = 0; ct < 4; ++ct)
        acc[rt][ct] =
            __builtin_amdgcn_mfma_f32_16x16x32_bf16(af[rt], bfv[ct], acc[rt][ct], 0, 0, 0);
    __syncthreads();
  }

#pragma unroll
  for (int rt = 0; rt < 4; ++rt) {
    int row0 = rowBase + wr * 64 + rt * 16 + qd * 4;
#pragma unroll
    for (int ct = 0; ct < 4; ++ct) {
      int col = colBase + wc * 64 + ct * 16 + ln;
      f32x4 a = acc[rt][ct];
      if constexpr (MODE == 2) {
        short* Co = (short*)C + (size_t)z * sC;
#pragma unroll
        for (int r = 0; r < 4; ++r)
          Co[(size_t)(row0 + r) * ldC + col] = f2b(a[r] * Lz[row0 + r]);
      } else if constexpr (MODE == 3) {
        short* Co = (short*)C + (size_t)z * sC;
#pragma unroll
        for (int r = 0; r < 4; ++r) Co[(size_t)(row0 + r) * ldC + col] = f2b(a[r]);
      } else {  // MODE 4
        float* Co = (float*)C + (size_t)z * sC;
        float bb = bias[col];
#pragma unroll
        for (int r = 0; r < 4; ++r) Co[(size_t)(row0 + r) * ldC + col] = a[r] + bb;
      }
    }
  }
}

extern "C" void kernel_launch(void* const* d_in, const int* in_sizes, int n_in,
                              void* d_out, int out_size, void* d_ws, size_t ws_size,
                              hipStream_t stream) {
  const float* vf = (const float*)d_in[0];
  const float* lf = (const float*)d_in[1];
  const float* Wv = (const float*)d_in[2];
  const float* bv = (const float*)d_in[3];
  const float* Wl = (const float*)d_in[4];
  const float* bl = (const float*)d_in[5];
  const float* Wo = (const float*)d_in[6];
  const float* bo = (const float*)d_in[7];

  constexpr int Bz = 8, L = 2048, D = 768, M = Bz * L, D2 = 2 * D;
  constexpr size_t PLANE = (size_t)M * D;

  // ---- workspace layout (92.4 MB — identical to round-4 passing layout) ----
  char* wp = (char*)d_ws;
  auto alloc = [&](size_t bytes) {
    char* p = wp;
    wp += (bytes + 255) & ~(size_t)255;
    return p;
  };
  short* vp_hi = (short*)alloc(PLANE * 2);               // 25.2 MB; -> al after av
  short* P     = (short*)alloc((size_t)Bz * L * L * 2);  // 67.1 MB; -> out_tmp after al
  float* invL  = (float*)alloc((size_t)M * 4);           // 64 KB
  short* al      = vp_hi;
  float* out_tmp = (float*)P;

  // ---- d_out as scratch: lp_hi | lp_lo planes ----
  short* lp_hi = (short*)d_out;
  short* lp_lo = lp_hi + PLANE;
  short* av    = lp_lo;  // lp_lo dead after sim

  // 1) both projections, fused 3-seg, single dispatch (z: 0=vision, 1=language)
  proj3_kernel<<<dim3(D / 128, M / 128, 2), 256, 0, stream>>>(
      vf, lf, Wv, Wl, bv, bl, vp_hi, lp_hi, lp_lo);

  // 2) P = exp(vp*lp^T - 20), fused 2-seg, glds staging
  sim2_kernel<<<dim3(L / 128, L / 128, Bz), 256, 0, stream>>>(vp_hi, lp_hi, lp_lo, P);

  // 3) invL[row] = 1 / sum_j P[row, j]
  rowsum_kernel<<<dim3(M / 4), 256, 0, stream>>>(P, invL);

  // 4) aligned_vision = (P @ vp) * invL[row] -> av (over dead lp_lo)
  gemm_k<2, false, true, false, false, false><<<dim3(D / 128, L / 128, Bz), 256, 0, stream>>>(
      P, nullptr, vp_hi, av, nullptr, invL, L, L, D, D, (long)L * L, (long)L * D,
      (long)L * D, (long)L);

  // 5) aligned_language = P^T @ (lp * invL[k]) -> al (over dead vp_hi)
  gemm_k<3, true, true, true, false, false><<<dim3(D / 128, L / 128, Bz), 256, 0, stream>>>(
      P, nullptr, lp_hi, al, nullptr, invL, L, L, D, D, (long)L * L, (long)L * D,
      (long)L * D, (long)L);

  // 6) out = [av | al] @ Wo^T + bo -> out_tmp (over dead P), fp32
  gemm_k<4, false, false, false, true, true><<<dim3(D / 128, M / 128, 1), 256, 0, stream>>>(
      av, al, Wo, out_tmp, bo, nullptr, D2, D, D2, D, 0, 0, 0, 0);

  // 7) out_tmp -> d_out
  hipMemcpyAsync(d_out, out_tmp, (size_t)M * D * 4, hipMemcpyDeviceToDevice, stream);
}

// Round 6
// 692.014 us; speedup vs baseline: 1.4770x; 1.0273x over previous
//
#include <hip/hip_runtime.h>
#include <stdint.h>

typedef __attribute__((ext_vector_type(8))) short bf16x8;
typedef __attribute__((ext_vector_type(4))) float f32x4;

__device__ __forceinline__ float b2f(short h) {
  return __uint_as_float(((unsigned)(unsigned short)h) << 16);
}
__device__ __forceinline__ short f2b(float f) {
  unsigned u = __float_as_uint(f);
  u += 0x7fffu + ((u >> 16) & 1u);
  return (short)(u >> 16);
}

// async global->LDS, 16 B per lane (global_load_lds_dwordx4)
__device__ __forceinline__ void glds16(const void* g, void* l) {
  __builtin_amdgcn_global_load_lds(
      (const __attribute__((address_space(1))) void*)g,
      (__attribute__((address_space(3))) void*)l, 16, 0, 0);
}

// XCD-aware decode: 1-D grid; the C col-tiles of one row-strip land on one XCD
// (consecutive slots), row-strips partitioned across XCDs. Bijective for
// total = 8 * RSX * C, RSX = row-strips per XCD, RPZ = row-strips per z.
__device__ __forceinline__ void xcd_decode(int C, int RSX, int RPZ,
                                           int& z, int& rowB, int& colB) {
  int id = blockIdx.x;
  int xcd = id & 7, slot = id >> 3;
  int rs = xcd * RSX + slot / C;
  colB = (slot % C) * 128;
  z = rs / RPZ;
  rowB = (rs % RPZ) * 128;
}

// ---------------- row sums of P (bf16, 2048 cols) -> store 1/sum ----------------
__global__ __launch_bounds__(256) void rowsum_kernel(const short* __restrict__ P,
                                                     float* __restrict__ invL) {
  int wave = threadIdx.x >> 6, lane = threadIdx.x & 63;
  size_t row = (size_t)blockIdx.x * 4 + wave;
  const short* p = P + row * 2048;
  float s = 0.f;
#pragma unroll
  for (int it = 0; it < 4; ++it) {
    bf16x8 x = *reinterpret_cast<const bf16x8*>(&p[it * 512 + lane * 8]);
#pragma unroll
    for (int j = 0; j < 8; ++j) s += b2f(x[j]);
  }
#pragma unroll
  for (int m = 32; m; m >>= 1) s += __shfl_xor(s, m);
  if (lane == 0) invL[row] = 1.0f / s;
}

// =================================================================================
// proj3: fused 3-segment split projection, both projections in one dispatch.
// z==0: A=Vf,B=Wv,bias=bv -> vp_hi.   z==1: A=Lf,B=Wl,bias=bl -> lp_hi + lp_lo.
// =================================================================================
__global__ __launch_bounds__(256) void proj3_kernel(
    const float* __restrict__ Vf, const float* __restrict__ Lf,
    const float* __restrict__ Wv, const float* __restrict__ Wl,
    const float* __restrict__ bv, const float* __restrict__ bl,
    short* __restrict__ vp_hi, short* __restrict__ lp_hi, short* __restrict__ lp_lo) {
  __shared__ alignas(16) short AsH[128 * 32];
  __shared__ alignas(16) short AsL[128 * 32];
  __shared__ alignas(16) short BsH[128 * 32];
  __shared__ alignas(16) short BsL[128 * 32];
  const int tid = threadIdx.x;
  int z, rowBase, colBase;
  xcd_decode(6, 32, 128, z, rowBase, colBase);  // total 1536 = 8*32*6
  const float* Af = z ? Lf : Vf;
  const float* Bf = z ? Wl : Wv;
  const float* bias = z ? bl : bv;
  const int lane = tid & 63;
  const int ln = lane & 15;
  const int qd = lane >> 4;
  const int w = tid >> 6;
  const int wr = w >> 1, wc = w & 1;

  f32x4 acc[4][4];
#pragma unroll
  for (int i = 0; i < 4; ++i)
#pragma unroll
    for (int j = 0; j < 4; ++j) acc[i][j] = 0.f;

  for (int kb = 0; kb < 768; kb += 32) {
#pragma unroll
    for (int q = 0; q < 2; ++q) {
      int c = q * 256 + tid;
      int r = c >> 2;
      int k0 = (c & 3) << 3;
      int sw = k0 ^ ((r & 3) << 3);
      {
        const float* p = &Af[(size_t)(rowBase + r) * 768 + kb + k0];
        float4 v0 = *reinterpret_cast<const float4*>(p);
        float4 v1 = *reinterpret_cast<const float4*>(p + 4);
        float vv[8] = {v0.x, v0.y, v0.z, v0.w, v1.x, v1.y, v1.z, v1.w};
        bf16x8 th, tl;
#pragma unroll
        for (int s = 0; s < 8; ++s) {
          short h = f2b(vv[s]);
          th[s] = h;
          tl[s] = f2b(vv[s] - b2f(h));
        }
        *reinterpret_cast<bf16x8*>(&AsH[r * 32 + sw]) = th;
        *reinterpret_cast<bf16x8*>(&AsL[r * 32 + sw]) = tl;
      }
      {
        const float* p = &Bf[(size_t)(colBase + r) * 768 + kb + k0];
        float4 v0 = *reinterpret_cast<const float4*>(p);
        float4 v1 = *reinterpret_cast<const float4*>(p + 4);
        float vv[8] = {v0.x, v0.y, v0.z, v0.w, v1.x, v1.y, v1.z, v1.w};
        bf16x8 th, tl;
#pragma unroll
        for (int s = 0; s < 8; ++s) {
          short h = f2b(vv[s]);
          th[s] = h;
          tl[s] = f2b(vv[s] - b2f(h));
        }
        *reinterpret_cast<bf16x8*>(&BsH[r * 32 + sw]) = th;
        *reinterpret_cast<bf16x8*>(&BsL[r * 32 + sw]) = tl;
      }
    }
    __syncthreads();
    bf16x8 ah[4], bh[4], tf[4];
#pragma unroll
    for (int rt = 0; rt < 4; ++rt) {
      int m = wr * 64 + rt * 16 + ln;
      ah[rt] = *reinterpret_cast<const bf16x8*>(&AsH[m * 32 + ((qd * 8) ^ ((m & 3) << 3))]);
    }
#pragma unroll
    for (int ct = 0; ct < 4; ++ct) {
      int n = wc * 64 + ct * 16 + ln;
      bh[ct] = *reinterpret_cast<const bf16x8*>(&BsH[n * 32 + ((qd * 8) ^ ((n & 3) << 3))]);
    }
#pragma unroll
    for (int rt = 0; rt < 4; ++rt)
#pragma unroll
      for (int ct = 0; ct < 4; ++ct)
        acc[rt][ct] = __builtin_amdgcn_mfma_f32_16x16x32_bf16(ah[rt], bh[ct], acc[rt][ct], 0, 0, 0);
#pragma unroll
    for (int rt = 0; rt < 4; ++rt) {
      int m = wr * 64 + rt * 16 + ln;
      tf[rt] = *reinterpret_cast<const bf16x8*>(&AsL[m * 32 + ((qd * 8) ^ ((m & 3) << 3))]);
    }
#pragma unroll
    for (int rt = 0; rt < 4; ++rt)
#pragma unroll
      for (int ct = 0; ct < 4; ++ct)
        acc[rt][ct] = __builtin_amdgcn_mfma_f32_16x16x32_bf16(tf[rt], bh[ct], acc[rt][ct], 0, 0, 0);
#pragma unroll
    for (int ct = 0; ct < 4; ++ct) {
      int n = wc * 64 + ct * 16 + ln;
      tf[ct] = *reinterpret_cast<const bf16x8*>(&BsL[n * 32 + ((qd * 8) ^ ((n & 3) << 3))]);
    }
#pragma unroll
    for (int rt = 0; rt < 4; ++rt)
#pragma unroll
      for (int ct = 0; ct < 4; ++ct)
        acc[rt][ct] = __builtin_amdgcn_mfma_f32_16x16x32_bf16(ah[rt], tf[ct], acc[rt][ct], 0, 0, 0);
    __syncthreads();
  }

#pragma unroll
  for (int rt = 0; rt < 4; ++rt) {
    int row0 = rowBase + wr * 64 + rt * 16 + qd * 4;
#pragma unroll
    for (int ct = 0; ct < 4; ++ct) {
      int col = colBase + wc * 64 + ct * 16 + ln;
      float bb = bias[col];
      f32x4 a = acc[rt][ct];
      if (z == 0) {
#pragma unroll
        for (int r = 0; r < 4; ++r)
          vp_hi[(size_t)(row0 + r) * 768 + col] = f2b(a[r] + bb);
      } else {
#pragma unroll
        for (int r = 0; r < 4; ++r) {
          float val = a[r] + bb;
          short h = f2b(val);
          lp_hi[(size_t)(row0 + r) * 768 + col] = h;
          lp_lo[(size_t)(row0 + r) * 768 + col] = f2b(val - b2f(h));
        }
      }
    }
  }
}

// =================================================================================
// sim2: P = exp(vp_hi*(lp_hi+lp_lo)^T - 20), fused 2 products per K-tile.
// glds staging, plain LDS layout.
// =================================================================================
__global__ __launch_bounds__(256) void sim2_kernel(const short* __restrict__ vp,
                                                   const short* __restrict__ lph,
                                                   const short* __restrict__ lpl,
                                                   short* __restrict__ P) {
  __shared__ alignas(16) short As[128 * 32];
  __shared__ alignas(16) short Bh[128 * 32];
  __shared__ alignas(16) short Bl[128 * 32];
  const int tid = threadIdx.x;
  int z, rowBase, colBase;
  xcd_decode(16, 16, 16, z, rowBase, colBase);  // total 2048 = 8*16*16
  const short* Az = vp + (size_t)z * 2048 * 768;
  const short* B0 = lph + (size_t)z * 2048 * 768;
  const short* B1 = lpl + (size_t)z * 2048 * 768;
  const int lane = tid & 63;
  const int ln = lane & 15;
  const int qd = lane >> 4;
  const int w = tid >> 6;
  const int wr = w >> 1, wc = w & 1;

  f32x4 acc[4][4];
#pragma unroll
  for (int i = 0; i < 4; ++i)
#pragma unroll
    for (int j = 0; j < 4; ++j) acc[i][j] = 0.f;

  for (int kb = 0; kb < 768; kb += 32) {
#pragma unroll
    for (int q = 0; q < 2; ++q) {
      int c = q * 256 + tid;
      int r = c >> 2;
      int k0 = (c & 3) << 3;
      glds16(&Az[(size_t)(rowBase + r) * 768 + kb + k0], &As[c * 8]);
      glds16(&B0[(size_t)(colBase + r) * 768 + kb + k0], &Bh[c * 8]);
      glds16(&B1[(size_t)(colBase + r) * 768 + kb + k0], &Bl[c * 8]);
    }
    __syncthreads();
    bf16x8 af[4], bf[4];
#pragma unroll
    for (int rt = 0; rt < 4; ++rt)
      af[rt] = *reinterpret_cast<const bf16x8*>(&As[(wr * 64 + rt * 16 + ln) * 32 + qd * 8]);
#pragma unroll
    for (int ct = 0; ct < 4; ++ct)
      bf[ct] = *reinterpret_cast<const bf16x8*>(&Bh[(wc * 64 + ct * 16 + ln) * 32 + qd * 8]);
#pragma unroll
    for (int rt = 0; rt < 4; ++rt)
#pragma unroll
      for (int ct = 0; ct < 4; ++ct)
        acc[rt][ct] = __builtin_amdgcn_mfma_f32_16x16x32_bf16(af[rt], bf[ct], acc[rt][ct], 0, 0, 0);
#pragma unroll
    for (int ct = 0; ct < 4; ++ct)
      bf[ct] = *reinterpret_cast<const bf16x8*>(&Bl[(wc * 64 + ct * 16 + ln) * 32 + qd * 8]);
#pragma unroll
    for (int rt = 0; rt < 4; ++rt)
#pragma unroll
      for (int ct = 0; ct < 4; ++ct)
        acc[rt][ct] = __builtin_amdgcn_mfma_f32_16x16x32_bf16(af[rt], bf[ct], acc[rt][ct], 0, 0, 0);
    __syncthreads();
  }

  short* Pz = P + (size_t)z * 2048 * 2048;
#pragma unroll
  for (int rt = 0; rt < 4; ++rt) {
    int row0 = rowBase + wr * 64 + rt * 16 + qd * 4;
#pragma unroll
    for (int ct = 0; ct < 4; ++ct) {
      int col = colBase + wc * 64 + ct * 16 + ln;
      f32x4 a = acc[rt][ct];
#pragma unroll
      for (int r = 0; r < 4; ++r)
        Pz[(size_t)(row0 + r) * 2048 + col] = f2b(__expf(a[r] - 20.0f));
    }
  }
}

// =================================================================================
// gemm_k: C[m,n] = sum_k A[m,k]*B[n,k], plain bf16. Plain operands via glds.
// TA/TB: operand given as [K,M]/[K,N] -> register-transpose staging (swizzled).
// SB: scale B by invL[k]. BF32: B fp32. DUALA: A split 768|768.
// MODE 2: bf16 = acc*invL[row]; MODE 3: bf16 = acc; MODE 4: fp32 = acc+bias[col]
// =================================================================================
template <int MODE, bool TA, bool TB, bool SB, bool BF32, bool DUALA>
__global__ __launch_bounds__(256) void gemm_k(const short* __restrict__ A,
                                              const short* __restrict__ A2,
                                              const void* __restrict__ B,
                                              void* __restrict__ C,
                                              const float* __restrict__ bias,
                                              const float* __restrict__ invL,
                                              int C_, int RSX_, int RPZ_,
                                              int K, int ldA, int ldB, int ldC,
                                              long sA, long sB, long sC, long sL) {
  __shared__ alignas(16) short As[128 * 32];
  __shared__ alignas(16) short Bs[128 * 32];
  const int tid = threadIdx.x;
  int z, rowBase, colBase;
  xcd_decode(C_, RSX_, RPZ_, z, rowBase, colBase);
  const short* Az = A + (size_t)z * sA;
  const float* Lz = invL ? (invL + (size_t)z * sL) : nullptr;
  const int lane = tid & 63;
  const int ln = lane & 15;
  const int qd = lane >> 4;
  const int w = tid >> 6;
  const int wr = w >> 1, wc = w & 1;
  constexpr bool GA = !TA;
  constexpr bool GB = !TB && !BF32;

  f32x4 acc[4][4];
#pragma unroll
  for (int i = 0; i < 4; ++i)
#pragma unroll
    for (int j = 0; j < 4; ++j) acc[i][j] = 0.f;

  for (int kb = 0; kb < K; kb += 32) {
    if constexpr (GA) {
#pragma unroll
      for (int q = 0; q < 2; ++q) {
        int c = q * 256 + tid;
        int r = c >> 2;
        int k0 = (c & 3) << 3;
        int kk = kb + k0;
        const short* src;
        if constexpr (DUALA) {
          src = (kk < 768) ? &Az[(size_t)(rowBase + r) * 768 + kk]
                           : &A2[(size_t)(rowBase + r) * 768 + kk - 768];
        } else {
          src = &Az[(size_t)(rowBase + r) * ldA + kk];
        }
        glds16(src, &As[c * 8]);
      }
    } else {
#pragma unroll
      for (int q = 0; q < 2; ++q) {
        int task = q * 256 + tid;
        int m = task & 127;
        int kc = (task >> 7) << 3;
        bf16x8 t;
#pragma unroll
        for (int s = 0; s < 8; ++s)
          t[s] = Az[(size_t)(kb + kc + s) * ldA + rowBase + m];
        *reinterpret_cast<bf16x8*>(&As[m * 32 + (kc ^ ((m & 3) << 3))]) = t;
      }
    }
    if constexpr (TB) {
      const short* Bz = (const short*)B + (size_t)z * sB;
#pragma unroll
      for (int q = 0; q < 2; ++q) {
        int task = q * 256 + tid;
        int n = task & 127;
        int kc = (task >> 7) << 3;
        bf16x8 t;
#pragma unroll
        for (int s = 0; s < 8; ++s) {
          short v = Bz[(size_t)(kb + kc + s) * ldB + colBase + n];
          if constexpr (SB) v = f2b(b2f(v) * Lz[kb + kc + s]);
          t[s] = v;
        }
        *reinterpret_cast<bf16x8*>(&Bs[n * 32 + (kc ^ ((n & 3) << 3))]) = t;
      }
    } else if constexpr (BF32) {
      const float* Bf = (const float*)B + (size_t)z * sB;
#pragma unroll
      for (int q = 0; q < 2; ++q) {
        int c = q * 256 + tid;
        int r = c >> 2;
        int k0 = (c & 3) << 3;
        const float* p = &Bf[(size_t)(colBase + r) * ldB + kb + k0];
        float4 v0 = *reinterpret_cast<const float4*>(p);
        float4 v1 = *reinterpret_cast<const float4*>(p + 4);
        float vv[8] = {v0.x, v0.y, v0.z, v0.w, v1.x, v1.y, v1.z, v1.w};
        bf16x8 t;
#pragma unroll
        for (int s = 0; s < 8; ++s) t[s] = f2b(vv[s]);
        *reinterpret_cast<bf16x8*>(&Bs[r * 32 + (k0 ^ ((r & 3) << 3))]) = t;
      }
    } else {
      const short* Bz = (const short*)B + (size_t)z * sB;
#pragma unroll
      for (int q = 0; q < 2; ++q) {
        int c = q * 256 + tid;
        int r = c >> 2;
        int k0 = (c & 3) << 3;
        glds16(&Bz[(size_t)(colBase + r) * ldB + kb + k0], &Bs[c * 8]);
      }
    }
    __syncthreads();
    bf16x8 af[4], bfv[4];
#pragma unroll
    for (int rt = 0; rt < 4; ++rt) {
      int m = wr * 64 + rt * 16 + ln;
      int off = GA ? (qd * 8) : ((qd * 8) ^ ((m & 3) << 3));
      af[rt] = *reinterpret_cast<const bf16x8*>(&As[m * 32 + off]);
    }
#pragma unroll
    for (int ct = 0; ct < 4; ++ct) {
      int n = wc * 64 + ct * 16 + ln;
      int off = GB ? (qd * 8) : ((qd * 8) ^ ((n & 3) << 3));
      bfv[ct] = *reinterpret_cast<const bf16x8*>(&Bs[n * 32 + off]);
    }
#pragma unroll
    for (int rt = 0; rt < 4; ++rt)
#pragma unroll
      for (int ct = 0; ct < 4; ++ct)
        acc[rt][ct] =
            __builtin_amdgcn_mfma_f32_16x16x32_bf16(af[rt], bfv[ct], acc[rt][ct], 0, 0, 0);
    __syncthreads();
  }

#pragma unroll
  for (int rt = 0; rt < 4; ++rt) {
    int row0 = rowBase + wr * 64 + rt * 16 + qd * 4;
#pragma unroll
    for (int ct = 0; ct < 4; ++ct) {
      int col = colBase + wc * 64 + ct * 16 + ln;
      f32x4 a = acc[rt][ct];
      if constexpr (MODE == 2) {
        short* Co = (short*)C + (size_t)z * sC;
#pragma unroll
        for (int r = 0; r < 4; ++r)
          Co[(size_t)(row0 + r) * ldC + col] = f2b(a[r] * Lz[row0 + r]);
      } else if constexpr (MODE == 3) {
        short* Co = (short*)C + (size_t)z * sC;
#pragma unroll
        for (int r = 0; r < 4; ++r) Co[(size_t)(row0 + r) * ldC + col] = f2b(a[r]);
      } else {  // MODE 4
        float* Co = (float*)C + (size_t)z * sC;
        float bb = bias[col];
#pragma unroll
        for (int r = 0; r < 4; ++r) Co[(size_t)(row0 + r) * ldC + col] = a[r] + bb;
      }
    }
  }
}

extern "C" void kernel_launch(void* const* d_in, const int* in_sizes, int n_in,
                              void* d_out, int out_size, void* d_ws, size_t ws_size,
                              hipStream_t stream) {
  const float* vf = (const float*)d_in[0];
  const float* lf = (const float*)d_in[1];
  const float* Wv = (const float*)d_in[2];
  const float* bv = (const float*)d_in[3];
  const float* Wl = (const float*)d_in[4];
  const float* bl = (const float*)d_in[5];
  const float* Wo = (const float*)d_in[6];
  const float* bo = (const float*)d_in[7];

  constexpr int Bz = 8, L = 2048, D = 768, M = Bz * L, D2 = 2 * D;
  constexpr size_t PLANE = (size_t)M * D;

  char* wp = (char*)d_ws;
  auto alloc = [&](size_t bytes) {
    char* p = wp;
    wp += (bytes + 255) & ~(size_t)255;
    return p;
  };
  short* vp_hi = (short*)alloc(PLANE * 2);               // 25.2 MB; -> al after av
  short* P     = (short*)alloc((size_t)Bz * L * L * 2);  // 67.1 MB; -> out_tmp after al
  float* invL  = (float*)alloc((size_t)M * 4);           // 64 KB
  short* al      = vp_hi;
  float* out_tmp = (float*)P;

  short* lp_hi = (short*)d_out;
  short* lp_lo = lp_hi + PLANE;
  short* av    = lp_lo;  // lp_lo dead after sim

  // 1) both projections, fused 3-seg. 1536 blocks = 8 XCD * 32 rs * 6 col
  proj3_kernel<<<dim3(1536), 256, 0, stream>>>(vf, lf, Wv, Wl, bv, bl, vp_hi, lp_hi, lp_lo);

  // 2) P = exp(vp*lp^T - 20). 2048 blocks = 8 * 16 * 16
  sim2_kernel<<<dim3(2048), 256, 0, stream>>>(vp_hi, lp_hi, lp_lo, P);

  // 3) invL
  rowsum_kernel<<<dim3(M / 4), 256, 0, stream>>>(P, invL);

  // 4) aligned_vision = (P @ vp) * invL[row] -> av.  768 blocks = 8 * 16 * 6
  gemm_k<2, false, true, false, false, false><<<dim3(768), 256, 0, stream>>>(
      P, nullptr, vp_hi, av, nullptr, invL, 6, 16, 16, L, L, D, D,
      (long)L * L, (long)L * D, (long)L * D, (long)L);

  // 5) aligned_language = P^T @ (lp * invL[k]) -> al.  768 blocks
  gemm_k<3, true, true, true, false, false><<<dim3(768), 256, 0, stream>>>(
      P, nullptr, lp_hi, al, nullptr, invL, 6, 16, 16, L, L, D, D,
      (long)L * L, (long)L * D, (long)L * D, (long)L);

  // 6) out = [av | al] @ Wo^T + bo -> out_tmp (fp32). 768 blocks = 8 * 16 * 6, z=0
  gemm_k<4, false, false, false, true, true><<<dim3(768), 256, 0, stream>>>(
      av, al, Wo, out_tmp, bo, nullptr, 6, 16, 128, D2, D, D2, D, 0, 0, 0, 0);

  // 7) out_tmp -> d_out
  hipMemcpyAsync(d_out, out_tmp, (size_t)M * D * 4, hipMemcpyDeviceToDevice, stream);
}